// Round 9
// baseline (2450.350 us; speedup 1.0000x reference)
//
#include <hip/hip_runtime.h>

#define N_NODES 200000
#define N_EDGES 800000
#define N_RULES 50000
#define NLAYERS 24
#define SCAN_NB 196        // ceil(200000/1024)
#define RP_STRIDE 200064   // ints per rp array (padded)

typedef short bf16x8 __attribute__((ext_vector_type(8)));
typedef float floatx4 __attribute__((ext_vector_type(4)));

__device__ __forceinline__ unsigned short f2bf(float f) {
  unsigned int b = __float_as_uint(f);
  b += 0x7FFFu + ((b >> 16) & 1u);          // round-to-nearest-even
  return (unsigned short)(b >> 16);
}
__device__ __forceinline__ float bf2f(unsigned short u) {
  return __uint_as_float(((unsigned int)u) << 16);
}

// ---------------- CSR build (unpadded; rank captured in hist) ----------------

__global__ void k_hist(const int* __restrict__ src, const int* __restrict__ tgt,
                       int* __restrict__ deg_out, int* __restrict__ deg_back,
                       int* __restrict__ rank_out, int* __restrict__ rank_back) {
  int e = blockIdx.x * 256 + threadIdx.x;   // E = 3125*256 exact
  rank_out[e]  = atomicAdd(&deg_out[tgt[e]], 1);   // rank = old count
  rank_back[e] = atomicAdd(&deg_back[src[e]], 1);
}

__global__ void k_scanA(const int* __restrict__ deg, int* __restrict__ part) {
  int y = blockIdx.y;
  const int* d = deg + y * N_NODES;
  __shared__ int sh[256];
  int t = threadIdx.x;
  int base = blockIdx.x * 1024 + t * 4;
  int s = 0;
  #pragma unroll
  for (int k = 0; k < 4; ++k) { int i = base + k; if (i < N_NODES) s += d[i]; }
  sh[t] = s; __syncthreads();
  for (int off = 128; off > 0; off >>= 1) { if (t < off) sh[t] += sh[t + off]; __syncthreads(); }
  if (t == 0) part[y * SCAN_NB + blockIdx.x] = sh[0];
}

__global__ void k_scanB(int* __restrict__ part, int* __restrict__ rp) {
  int y = blockIdx.y;
  __shared__ int buf[256];
  int t = threadIdx.x;
  int v = (t < SCAN_NB) ? part[y * SCAN_NB + t] : 0;
  buf[t] = v; __syncthreads();
  for (int off = 1; off < 256; off <<= 1) {
    int x = (t >= off) ? buf[t - off] : 0;
    __syncthreads();
    buf[t] += x;
    __syncthreads();
  }
  if (t < SCAN_NB) part[y * SCAN_NB + t] = buf[t] - v;   // exclusive
  if (t == 0) rp[y * RP_STRIDE + N_NODES] = N_EDGES;
}

__global__ void k_scanC(const int* __restrict__ deg, const int* __restrict__ part,
                        int* __restrict__ rp) {
  int y = blockIdx.y;
  const int* d = deg + y * N_NODES;
  int* r = rp + y * RP_STRIDE;
  __shared__ int buf[256];
  int t = threadIdx.x;
  int base = blockIdx.x * 1024 + t * 4;
  int dv[4]; int s = 0;
  #pragma unroll
  for (int k = 0; k < 4; ++k) { int i = base + k; dv[k] = (i < N_NODES) ? d[i] : 0; s += dv[k]; }
  buf[t] = s; __syncthreads();
  int sv = s;
  for (int off = 1; off < 256; off <<= 1) {
    int x = (t >= off) ? buf[t - off] : 0;
    __syncthreads();
    buf[t] += x;
    __syncthreads();
  }
  int e = part[y * SCAN_NB + blockIdx.x] + buf[t] - sv;
  #pragma unroll
  for (int k = 0; k < 4; ++k) { int i = base + k; if (i < N_NODES) r[i] = e; e += dv[k]; }
}

// atomic-free fill: slot = rp[node] + rank[e]
__global__ void k_fill(const int* __restrict__ src, const int* __restrict__ tgt,
                       const int* __restrict__ rp_out, const int* __restrict__ rp_back,
                       const int* __restrict__ rank_out, const int* __restrict__ rank_back,
                       int* __restrict__ ci_out, int* __restrict__ ci_back) {
  int e = blockIdx.x * 256 + threadIdx.x;
  int s = src[e], t = tgt[e];
  ci_out[rp_out[t] + rank_out[e]] = s;
  ci_back[rp_back[s] + rank_back[e]] = t;
}

// ---------------- BN-folded weight prep (bf16 MFMA A-fragments) ----------------
__global__ void k_prep(const float* __restrict__ W, const float* __restrict__ b,
                       const float* __restrict__ gamma, const float* __restrict__ beta,
                       const float* __restrict__ rmean, const float* __restrict__ rvar,
                       unsigned short* __restrict__ WpF, float* __restrict__ bp) {
  int d = blockIdx.x, l = blockIdx.y, lane = threadIdx.x;
  int ld = l * 2 + d;
  __shared__ float s_s[64], t_s[64];
  float s = gamma[ld * 64 + lane] * rsqrtf(rvar[ld * 64 + lane] + 1e-5f);
  s_s[lane] = s;
  t_s[lane] = beta[ld * 64 + lane] - rmean[ld * 64 + lane] * s;
  __syncthreads();
  float bias = b[ld * 64 + lane];
  for (int j = 0; j < 64; ++j) bias += W[(ld * 64 + lane) * 64 + j] * t_s[j];
  bp[ld * 64 + lane] = bias;
  #pragma unroll
  for (int f = 0; f < 8; ++f) {
    int ct = f >> 1, kh = f & 1;
    int row = ct * 16 + (lane & 15);
    #pragma unroll
    for (int jj = 0; jj < 8; ++jj) {
      int k = kh * 32 + (lane >> 4) * 8 + jj;
      float val = W[(ld * 64 + row) * 64 + k] * s_s[k];
      WpF[(ld * 8 + f) * 512 + lane * 8 + jj] = f2bf(val);
    }
  }
}

// ---------------- Wh prep: split bf16 hi/lo MFMA A-fragments ----------------
__global__ void k_prep2(const float* __restrict__ Wh,
                        unsigned short* __restrict__ WhFhi,
                        unsigned short* __restrict__ WhFlo) {
  int jt = blockIdx.x, lane = threadIdx.x;
  #pragma unroll
  for (int kh = 0; kh < 2; ++kh) {
    #pragma unroll
    for (int jj = 0; jj < 8; ++jj) {
      int j = jt * 16 + (lane & 15);
      int k = kh * 32 + (lane >> 4) * 8 + jj;
      float wv = Wh[j * 64 + k];
      unsigned short hi = f2bf(wv);
      WhFhi[(jt * 2 + kh) * 512 + lane * 8 + jj] = hi;
      WhFlo[(jt * 2 + kh) * 512 + lane * 8 + jj] = f2bf(wv - bf2f(hi));
    }
  }
}

// ---------------- embedding gather (bf16 hi/lo master) ----------------
__global__ void k_embed(const int* __restrict__ nodes, const float* __restrict__ emb,
                        unsigned short* __restrict__ hi_a,
                        unsigned short* __restrict__ lo) {
  int gid = blockIdx.x * 256 + threadIdx.x;     // N*64 = 50000*256 exact
  int i = gid >> 6, c = gid & 63;
  float v = emb[nodes[i] * 64 + c];
  unsigned short h = f2bf(v);
  hi_a[gid] = h;
  lo[gid] = f2bf(v - bf2f(h));
}

// ---------------- fused layer (round-18 structure) --------------------------
// R13's proven 32-loads-in-flight, but each load covers 2 EDGES: lanes 0-31
// read row A (nodes 0-7 stream), lanes 32-63 read row B (nodes 8-15 stream),
// 4B/lane = 2 bf16 channels. Stream bookkeeping (j/ce/cur, flush) is SCALAR
// (readlane -> SGPR branches); only address select + accumulate are vector.
// Per iteration 32 loads cover 128 edges (2x R13 coverage, same depth).
__global__ __launch_bounds__(256, 6) void k_layer(
    const unsigned short* __restrict__ hi_in,      // gather source + master hi
    unsigned short* __restrict__ hi_out,
    unsigned short* __restrict__ lo,               // master lo (in-place)
    const int* __restrict__ rp0, const int* __restrict__ ci0,
    const int* __restrict__ rp1, const int* __restrict__ ci1,
    const unsigned short* __restrict__ WfL, const float* __restrict__ bpL) {
  __shared__ __align__(16) unsigned short m_s[4][2][16 * 72];  // [warp][dir], bf16, pitch 72
  __shared__ float bp_s[128];
  int tid = threadIdx.x, lane = tid & 63, w = tid >> 6;
  if (tid < 128) bp_s[tid] = bpL[tid];
  __syncthreads();
  int base = (blockIdx.x * 4 + w) * 16;
  int n15 = lane & 15, q = lane >> 4;
  int c2 = lane & 31;                       // uint (2-channel) index within row
  bool hihalf = lane >= 32;                 // lanes>=32 serve stream B
  const unsigned int* hp = (const unsigned int*)hi_in;

  // rp for BOTH dirs into registers
  int rpv0 = (lane < 17) ? rp0[base + lane] : 0;
  int rpv1 = (lane < 17) ? rp1[base + lane] : 0;
  int rs0 = __builtin_amdgcn_readlane(rpv0, 0);
  int rm0 = __builtin_amdgcn_readlane(rpv0, 8);
  int re0 = __builtin_amdgcn_readlane(rpv0, 16);
  int rs1 = __builtin_amdgcn_readlane(rpv1, 0);
  int rm1 = __builtin_amdgcn_readlane(rpv1, 8);
  int re1 = __builtin_amdgcn_readlane(rpv1, 16);
  // 4 half-wave streams: {dir0 nodes0-7, dir0 nodes8-15, dir1 0-7, dir1 8-15}
  int nbA0 = rm0 - rs0, nbB0 = re0 - rm0;
  int nbA1 = rm1 - rs1, nbB1 = re1 - rm1;

  int cvA0  = (lane < nbA0)      ? ci0[rs0 + lane]      : 0;
  int cvB0  = (lane < nbB0)      ? ci0[rm0 + lane]      : 0;
  int cvA1  = (lane < nbA1)      ? ci1[rs1 + lane]      : 0;
  int cvB1  = (lane < nbB1)      ? ci1[rm1 + lane]      : 0;
  int cvnA0 = (64 + lane < nbA0) ? ci0[rs0 + 64 + lane] : 0;
  int cvnB0 = (64 + lane < nbB0) ? ci0[rm0 + 64 + lane] : 0;
  int cvnA1 = (64 + lane < nbA1) ? ci1[rs1 + 64 + lane] : 0;
  int cvnB1 = (64 + lane < nbB1) ? ci1[rm1 + 64 + lane] : 0;

  int curA0 = 0, csA0 = rs0, ceA0 = __builtin_amdgcn_readlane(rpv0, 1);
  int curB0 = 8, csB0 = rm0, ceB0 = __builtin_amdgcn_readlane(rpv0, 9);
  int curA1 = 0, csA1 = rs1, ceA1 = __builtin_amdgcn_readlane(rpv1, 1);
  int curB1 = 8, csB1 = rm1, ceB1 = __builtin_amdgcn_readlane(rpv1, 9);
  float a00 = 0.f, a01 = 0.f;               // dir0: channels 2c2, 2c2+1
  float a10 = 0.f, a11 = 0.f;               // dir1

  int t0 = nbA0 > nbB0 ? nbA0 : nbB0;
  int t1 = nbA1 > nbB1 ? nbA1 : nbB1;
  int gmax0 = (t0 + 15) >> 4, gmax1 = (t1 + 15) >> 4;
  int gmax = gmax0 > gmax1 ? gmax0 : gmax1;

// issue 16 dual-row loads for one dir (32 edges); sn select per half-wave
#define ISSUE2(V, cvA, cvB, nbA, nbB)                                     \
  { int off_ = g << 4;                                                    \
    if (off_ < nbA || off_ < nbB) {                                       \
      int boff_ = off_ & 63;                                              \
      _Pragma("unroll")                                                   \
      for (int u = 0; u < 16; ++u) {                                      \
        int iA = __builtin_amdgcn_readlane(cvA, boff_ + u) << 5;          \
        int iB = __builtin_amdgcn_readlane(cvB, boff_ + u) << 5;          \
        int vi = (hihalf ? iB : iA) + c2;                                 \
        V[u] = hp[vi];                                                    \
      } } }

// advance a stream's cv double-buffer (entering a new 64-edge block)
#define ROLLS(cv, cvn, ci, rsS, nbS)                                      \
  { cv = cvn;                                                             \
    int ob_ = (g << 4) + 64;                                              \
    cvn = (ob_ + lane < nbS) ? ci[rsS + ob_ + lane] : 0; }

// flush one node of stream A (scalar control; vector write lanes<32)
#define FLUSHA(dirIdx, rpv, cur, cs, ce, x0, x1)                          \
  { int deg = ce - cs;                                                    \
    float invc = deg > 0 ? __builtin_amdgcn_rcpf((float)deg) : 0.f;       \
    if (lane < 32) {                                                      \
      unsigned int pk = (unsigned int)f2bf(x0 * invc)                     \
                      | ((unsigned int)f2bf(x1 * invc) << 16);            \
      *(unsigned int*)&m_s[w][dirIdx][cur * 72 + 2 * c2] = pk;            \
      x0 = 0.f; x1 = 0.f;                                                 \
    }                                                                     \
    cs = ce; cur++;                                                       \
    ce = __builtin_amdgcn_readlane(rpv, cur + 1); }

// flush one node of stream B (vector write lanes>=32)
#define FLUSHB(dirIdx, rpv, cur, cs, ce, x0, x1)                          \
  { int deg = ce - cs;                                                    \
    float invc = deg > 0 ? __builtin_amdgcn_rcpf((float)deg) : 0.f;       \
    if (lane >= 32) {                                                     \
      unsigned int pk = (unsigned int)f2bf(x0 * invc)                     \
                      | ((unsigned int)f2bf(x1 * invc) << 16);            \
      *(unsigned int*)&m_s[w][dirIdx][cur * 72 + 2 * c2] = pk;            \
      x0 = 0.f; x1 = 0.f;                                                 \
    }                                                                     \
    cs = ce; cur++;                                                       \
    ce = __builtin_amdgcn_readlane(rpv, cur + 1); }

// accumulate one dir's 16 dual-edges (scalar stream control)
#define ACCD(V, dirIdx, rpv, rsS, rmS, reS, nbA, nbB,                     \
             curA, csA, ceA, curB, csB, ceB, x0, x1)                      \
  { int off_ = g << 4;                                                    \
    if (off_ < nbA || off_ < nbB) {                                       \
      _Pragma("unroll")                                                   \
      for (int u = 0; u < 16; ++u) {                                      \
        int jA = rsS + off_ + u;                                          \
        int jB = rmS + off_ + u;                                          \
        bool okA = jA < rmS && off_ + u < nbA;                            \
        bool okB = jB < reS && off_ + u < nbB;                            \
        if (okA) { while (jA >= ceA) FLUSHA(dirIdx, rpv, curA, csA, ceA, x0, x1) } \
        if (okB) { while (jB >= ceB) FLUSHB(dirIdx, rpv, curB, csB, ceB, x0, x1) } \
        if (okA || okB) {                                                 \
          unsigned int uv = V[u];                                         \
          float e0 = __uint_as_float(uv << 16);                           \
          float e1 = __uint_as_float(uv & 0xffff0000u);                   \
          if (okA && okB) { x0 += e0; x1 += e1; }                         \
          else if (okA) { if (lane < 32)  { x0 += e0; x1 += e1; } }       \
          else          { if (lane >= 32) { x0 += e0; x1 += e1; } }       \
        } } } }

  unsigned int v0[16], v1[16];
  for (int g = 0; g < gmax; ++g) {
    if (g && ((g & 3) == 0)) {               // 64-block rollover, all streams
      ROLLS(cvA0, cvnA0, ci0, rs0, nbA0)
      ROLLS(cvB0, cvnB0, ci0, rm0, nbB0)
      ROLLS(cvA1, cvnA1, ci1, rs1, nbA1)
      ROLLS(cvB1, cvnB1, ci1, rm1, nbB1)
    }
    ISSUE2(v0, cvA0, cvB0, nbA0, nbB0)       // 32 loads in flight = 128 edges
    ISSUE2(v1, cvA1, cvB1, nbA1, nbB1)
    ACCD(v0, 0, rpv0, rs0, rm0, re0, nbA0, nbB0,
         curA0, csA0, ceA0, curB0, csB0, ceB0, a00, a01)
    ACCD(v1, 1, rpv1, rs1, rm1, re1, nbA1, nbB1,
         curA1, csA1, ceA1, curB1, csB1, ceB1, a10, a11)
  }
#undef ISSUE2
#undef ROLLS
#undef ACCD

// trailing flush for one stream pair
  #pragma unroll 1
  while (curA0 < 8)  FLUSHA(0, rpv0, curA0, csA0, ceA0, a00, a01)
  #pragma unroll 1
  while (curB0 < 16) FLUSHB(0, rpv0, curB0, csB0, ceB0, a00, a01)
  #pragma unroll 1
  while (curA1 < 8)  FLUSHA(1, rpv1, curA1, csA1, ceA1, a10, a11)
  #pragma unroll 1
  while (curB1 < 16) FLUSHB(1, rpv1, curB1, csB1, ceB1, a10, a11)
#undef FLUSHA
#undef FLUSHB

  // -------- MFMA both dirs; y into warp-private LDS scratch (reuses m_s) ----
  bf16x8 b0d0 = *(const bf16x8*)&m_s[w][0][n15 * 72 + q * 8];
  bf16x8 b1d0 = *(const bf16x8*)&m_s[w][0][n15 * 72 + 32 + q * 8];
  bf16x8 b0d1 = *(const bf16x8*)&m_s[w][1][n15 * 72 + q * 8];
  bf16x8 b1d1 = *(const bf16x8*)&m_s[w][1][n15 * 72 + 32 + q * 8];
  float* ys = (float*)&m_s[w][0][0];                   // 4352 B <= 4608 B region
  #pragma unroll
  for (int ct = 0; ct < 4; ++ct) {
    const unsigned short* wf0 = WfL + (ct * 2) * 512 + lane * 8;        // d0 frags
    const unsigned short* wf1 = WfL + 4096 + (ct * 2) * 512 + lane * 8; // d1 frags
    floatx4 d40 = {0.f, 0.f, 0.f, 0.f};
    floatx4 d41 = {0.f, 0.f, 0.f, 0.f};
    d40 = __builtin_amdgcn_mfma_f32_16x16x32_bf16(*(const bf16x8*)wf0, b0d0, d40, 0, 0, 0);
    d40 = __builtin_amdgcn_mfma_f32_16x16x32_bf16(*(const bf16x8*)(wf0 + 512), b1d0, d40, 0, 0, 0);
    d41 = __builtin_amdgcn_mfma_f32_16x16x32_bf16(*(const bf16x8*)wf1, b0d1, d41, 0, 0, 0);
    d41 = __builtin_amdgcn_mfma_f32_16x16x32_bf16(*(const bf16x8*)(wf1 + 512), b1d1, d41, 0, 0, 0);
    // D: col = n15 = node, row = ct*16 + q*4 + i = channel
    int c0 = ct * 16 + q * 4;
    floatx4 yv;
    #pragma unroll
    for (int i = 0; i < 4; ++i)
      yv[i] = fmaxf(d40[i] + bp_s[c0 + i], 0.f)
            + fmaxf(d41[i] + bp_s[64 + c0 + i], 0.f);
    *(floatx4*)&ys[n15 * 68 + c0] = yv;                // pitch 68 f32
  }

  // epilogue: row-major coalesced; residual on hi/lo, re-split, store
  #pragma unroll
  for (int r = 0; r < 16; ++r) {
    int gi = (base + r) * 64 + lane;
    float xv = bf2f(hi_in[gi]) + bf2f(lo[gi]) + ys[r * 68 + lane];
    unsigned short h = f2bf(xv);
    hi_out[gi] = h;
    lo[gi] = f2bf(xv - bf2f(h));   // in-place: only this warp touches these rows
  }
}

// ---------------- readout (MFMA; hi/lo split comes free from master format) ----
__global__ __launch_bounds__(256) void k_final(
    const unsigned short* __restrict__ hi, const unsigned short* __restrict__ lo,
    const int* __restrict__ rules,
    const unsigned short* __restrict__ WhFhi, const unsigned short* __restrict__ WhFlo,
    const float* __restrict__ bh, const float* __restrict__ Wo,
    float* __restrict__ out) {
  __shared__ __align__(16) float bh_s[1024], wo_s[1024];
  int tid = threadIdx.x, lane = tid & 63, w = tid >> 6;
  ((floatx4*)bh_s)[tid] = ((const floatx4*)bh)[tid];
  ((floatx4*)wo_s)[tid] = ((const floatx4*)Wo)[tid];
  __syncthreads();
  int n15 = lane & 15, q = lane >> 4;
  int rbase = (blockIdx.x * 4 + w) * 16;
  int ru = rbase + n15;
  int nd = rules[ru < N_RULES ? ru : N_RULES - 1];
  bf16x8 b0h = *(const bf16x8*)&hi[nd * 64 + q * 8];
  bf16x8 b1h = *(const bf16x8*)&hi[nd * 64 + 32 + q * 8];
  bf16x8 b0l = *(const bf16x8*)&lo[nd * 64 + q * 8];
  bf16x8 b1l = *(const bf16x8*)&lo[nd * 64 + 32 + q * 8];
  float acc = 0.f;
  #pragma unroll 4
  for (int jt = 0; jt < 64; ++jt) {
    const unsigned short* fh = WhFhi + (jt * 2) * 512 + lane * 8;
    const unsigned short* fl = WhFlo + (jt * 2) * 512 + lane * 8;
    bf16x8 a0h = *(const bf16x8*)fh;
    bf16x8 a1h = *(const bf16x8*)(fh + 512);
    bf16x8 a0l = *(const bf16x8*)fl;
    bf16x8 a1l = *(const bf16x8*)(fl + 512);
    floatx4 d4 = {0.f, 0.f, 0.f, 0.f};
    d4 = __builtin_amdgcn_mfma_f32_16x16x32_bf16(a0h, b0h, d4, 0, 0, 0);
    d4 = __builtin_amdgcn_mfma_f32_16x16x32_bf16(a1h, b1h, d4, 0, 0, 0);
    d4 = __builtin_amdgcn_mfma_f32_16x16x32_bf16(a0h, b0l, d4, 0, 0, 0);
    d4 = __builtin_amdgcn_mfma_f32_16x16x32_bf16(a1h, b1l, d4, 0, 0, 0);
    d4 = __builtin_amdgcn_mfma_f32_16x16x32_bf16(a0l, b0h, d4, 0, 0, 0);
    d4 = __builtin_amdgcn_mfma_f32_16x16x32_bf16(a1l, b1h, d4, 0, 0, 0);
    floatx4 bh4 = *(const floatx4*)&bh_s[jt * 16 + q * 4];
    floatx4 wo4 = *(const floatx4*)&wo_s[jt * 16 + q * 4];
    #pragma unroll
    for (int i = 0; i < 4; ++i)
      acc += fmaxf(d4[i] + bh4[i], 0.f) * wo4[i];
  }
  acc += __shfl_down(acc, 32);     // fold q2,q3 into q0,q1
  acc += __shfl_down(acc, 16);     // fold q1 into q0
  if (lane < 16 && rbase + lane < N_RULES) out[rbase + lane] = acc;
}

// ---------------- launch ----------------
extern "C" void kernel_launch(void* const* d_in, const int* in_sizes, int n_in,
                              void* d_out, int out_size, void* d_ws, size_t ws_size,
                              hipStream_t stream) {
  const int* nodes = (const int*)d_in[0];
  const int* sources = (const int*)d_in[1];
  const int* targets = (const int*)d_in[2];
  const int* rules = (const int*)d_in[3];
  const float* emb = (const float*)d_in[4];
  const float* W = (const float*)d_in[5];
  const float* b = (const float*)d_in[6];
  const float* gamma = (const float*)d_in[7];
  const float* beta = (const float*)d_in[8];
  const float* rmean = (const float*)d_in[9];
  const float* rvar = (const float*)d_in[10];
  const float* Wh = (const float*)d_in[11];
  const float* bh = (const float*)d_in[12];
  const float* Wo = (const float*)d_in[13];
  float* out = (float*)d_out;

  if (ws_size < 95100000u) return;  // need ~95.1 MB scratch

  char* ws = (char*)d_ws;
  unsigned short* hi_a = (unsigned short*)(ws + 0);          // 25.6 MB
  unsigned short* hi_b = (unsigned short*)(ws + 25600000);   // 25.6 MB
  unsigned short* lo   = (unsigned short*)(ws + 51200000);   // 25.6 MB
  int* deg_out  = (int*)(ws + 76800000);                     // 800 KB
  int* deg_back = (int*)(ws + 77600000);                     // 800 KB
  int* rank_out = (int*)(ws + 78400000);                     // 3.2 MB
  int* rank_back= (int*)(ws + 81600000);                     // 3.2 MB
  int* rp_out   = (int*)(ws + 84800000);                     // RP_STRIDE ints
  int* rp_back  = (int*)(ws + 85600256);
  int* ci_out   = (int*)(ws + 86400512);                     // 3.2 MB
  int* ci_back  = (int*)(ws + 89600512);                     // 3.2 MB
  int* part     = (int*)(ws + 92800512);                     // 1568 B
  unsigned short* WpF   = (unsigned short*)(ws + 92802080);  // 384 KB (16B aligned)
  float* bp             = (float*)(ws + 93195296);           // 12 KB
  unsigned short* WhFhi = (unsigned short*)(ws + 93207584);  // 128 KB
  unsigned short* WhFlo = (unsigned short*)(ws + 93338656);  // 128 KB -> ends 93,469,728

  // zero deg_out/deg_back (contiguous 1.6 MB)
  (void)hipMemsetAsync(deg_out, 0, 1600000u, stream);

  k_hist<<<3125, 256, 0, stream>>>(sources, targets, deg_out, deg_back,
                                   rank_out, rank_back);
  k_scanA<<<dim3(SCAN_NB, 2), 256, 0, stream>>>(deg_out, part);
  k_scanB<<<dim3(1, 2), 256, 0, stream>>>(part, rp_out);
  k_scanC<<<dim3(SCAN_NB, 2), 256, 0, stream>>>(deg_out, part, rp_out);
  k_fill<<<3125, 256, 0, stream>>>(sources, targets, rp_out, rp_back,
                                   rank_out, rank_back, ci_out, ci_back);
  k_prep<<<dim3(2, NLAYERS), 64, 0, stream>>>(W, b, gamma, beta, rmean, rvar, WpF, bp);
  k_prep2<<<64, 64, 0, stream>>>(Wh, WhFhi, WhFlo);
  k_embed<<<50000, 256, 0, stream>>>(nodes, emb, hi_a, lo);

  const unsigned short* hin = hi_a;
  unsigned short* hout = hi_b;
  for (int l = 0; l < NLAYERS; ++l) {
    k_layer<<<3125, 256, 0, stream>>>(hin, hout, lo,
                                      rp_out, ci_out, rp_back, ci_back,
                                      WpF + (size_t)l * 8192, bp + (size_t)l * 128);
    const unsigned short* tmp = hin; hin = hout; hout = (unsigned short*)tmp;
  }
  k_final<<<782, 256, 0, stream>>>(hin, lo, rules, WhFhi, WhFlo, bh, Wo, out);
}

// Round 10
// 1607.295 us; speedup vs baseline: 1.5245x; 1.5245x over previous
//
#include <hip/hip_runtime.h>

#define N_NODES 200000
#define N_EDGES 800000
#define N_RULES 50000
#define NLAYERS 24
#define SCAN_NB 196        // ceil(200000/1024)
#define RP_STRIDE 200064   // ints per rp array (padded)

typedef short bf16x8 __attribute__((ext_vector_type(8)));
typedef float floatx4 __attribute__((ext_vector_type(4)));

__device__ __forceinline__ unsigned short f2bf(float f) {
  unsigned int b = __float_as_uint(f);
  b += 0x7FFFu + ((b >> 16) & 1u);          // round-to-nearest-even
  return (unsigned short)(b >> 16);
}
__device__ __forceinline__ float bf2f(unsigned short u) {
  return __uint_as_float(((unsigned int)u) << 16);
}

// ---------------- CSR build ----------------
// round-19: k_hist does NON-RETURNING atomics only (waves retire without
// waiting on atomic responses); rank arrays deleted. k_scanC emits a mutable
// copy rpc of the row pointers; k_fill claims slots with returning atomicAdd
// on rpc (within-node order nondeterministic; mean is order-independent).

__global__ void k_hist(const int* __restrict__ src, const int* __restrict__ tgt,
                       int* __restrict__ deg_out, int* __restrict__ deg_back) {
  int e = blockIdx.x * 256 + threadIdx.x;   // E = 3125*256 exact
  atomicAdd(&deg_out[tgt[e]], 1);
  atomicAdd(&deg_back[src[e]], 1);
}

__global__ void k_scanA(const int* __restrict__ deg, int* __restrict__ part) {
  int y = blockIdx.y;
  const int* d = deg + y * N_NODES;
  __shared__ int sh[256];
  int t = threadIdx.x;
  int base = blockIdx.x * 1024 + t * 4;
  int s = 0;
  #pragma unroll
  for (int k = 0; k < 4; ++k) { int i = base + k; if (i < N_NODES) s += d[i]; }
  sh[t] = s; __syncthreads();
  for (int off = 128; off > 0; off >>= 1) { if (t < off) sh[t] += sh[t + off]; __syncthreads(); }
  if (t == 0) part[y * SCAN_NB + blockIdx.x] = sh[0];
}

__global__ void k_scanB(int* __restrict__ part, int* __restrict__ rp) {
  int y = blockIdx.y;
  __shared__ int buf[256];
  int t = threadIdx.x;
  int v = (t < SCAN_NB) ? part[y * SCAN_NB + t] : 0;
  buf[t] = v; __syncthreads();
  for (int off = 1; off < 256; off <<= 1) {
    int x = (t >= off) ? buf[t - off] : 0;
    __syncthreads();
    buf[t] += x;
    __syncthreads();
  }
  if (t < SCAN_NB) part[y * SCAN_NB + t] = buf[t] - v;   // exclusive
  if (t == 0) rp[y * RP_STRIDE + N_NODES] = N_EDGES;
}

__global__ void k_scanC(const int* __restrict__ deg, const int* __restrict__ part,
                        int* __restrict__ rp, int* __restrict__ rpc) {
  int y = blockIdx.y;
  const int* d = deg + y * N_NODES;
  int* r = rp + y * RP_STRIDE;
  int* rc = rpc + y * N_NODES;
  __shared__ int buf[256];
  int t = threadIdx.x;
  int base = blockIdx.x * 1024 + t * 4;
  int dv[4]; int s = 0;
  #pragma unroll
  for (int k = 0; k < 4; ++k) { int i = base + k; dv[k] = (i < N_NODES) ? d[i] : 0; s += dv[k]; }
  buf[t] = s; __syncthreads();
  int sv = s;
  for (int off = 1; off < 256; off <<= 1) {
    int x = (t >= off) ? buf[t - off] : 0;
    __syncthreads();
    buf[t] += x;
    __syncthreads();
  }
  int e = part[y * SCAN_NB + blockIdx.x] + buf[t] - sv;
  #pragma unroll
  for (int k = 0; k < 4; ++k) {
    int i = base + k;
    if (i < N_NODES) { r[i] = e; rc[i] = e; }
    e += dv[k];
  }
}

// CSR fill via returning atomics on the rpc copy (no rank arrays)
__global__ void k_fill(const int* __restrict__ src, const int* __restrict__ tgt,
                       int* __restrict__ rpc_out, int* __restrict__ rpc_back,
                       int* __restrict__ ci_out, int* __restrict__ ci_back) {
  int e = blockIdx.x * 256 + threadIdx.x;
  int s = src[e], t = tgt[e];
  ci_out[atomicAdd(&rpc_out[t], 1)] = s;
  ci_back[atomicAdd(&rpc_back[s], 1)] = t;
}

// ---------------- BN-folded weight prep (bf16 MFMA A-fragments) ----------------
__global__ void k_prep(const float* __restrict__ W, const float* __restrict__ b,
                       const float* __restrict__ gamma, const float* __restrict__ beta,
                       const float* __restrict__ rmean, const float* __restrict__ rvar,
                       unsigned short* __restrict__ WpF, float* __restrict__ bp) {
  int d = blockIdx.x, l = blockIdx.y, lane = threadIdx.x;
  int ld = l * 2 + d;
  __shared__ float s_s[64], t_s[64];
  float s = gamma[ld * 64 + lane] * rsqrtf(rvar[ld * 64 + lane] + 1e-5f);
  s_s[lane] = s;
  t_s[lane] = beta[ld * 64 + lane] - rmean[ld * 64 + lane] * s;
  __syncthreads();
  float bias = b[ld * 64 + lane];
  for (int j = 0; j < 64; ++j) bias += W[(ld * 64 + lane) * 64 + j] * t_s[j];
  bp[ld * 64 + lane] = bias;
  #pragma unroll
  for (int f = 0; f < 8; ++f) {
    int ct = f >> 1, kh = f & 1;
    int row = ct * 16 + (lane & 15);
    #pragma unroll
    for (int jj = 0; jj < 8; ++jj) {
      int k = kh * 32 + (lane >> 4) * 8 + jj;
      float val = W[(ld * 64 + row) * 64 + k] * s_s[k];
      WpF[(ld * 8 + f) * 512 + lane * 8 + jj] = f2bf(val);
    }
  }
}

// ---------------- Wh prep: split bf16 hi/lo MFMA A-fragments ----------------
__global__ void k_prep2(const float* __restrict__ Wh,
                        unsigned short* __restrict__ WhFhi,
                        unsigned short* __restrict__ WhFlo) {
  int jt = blockIdx.x, lane = threadIdx.x;
  #pragma unroll
  for (int kh = 0; kh < 2; ++kh) {
    #pragma unroll
    for (int jj = 0; jj < 8; ++jj) {
      int j = jt * 16 + (lane & 15);
      int k = kh * 32 + (lane >> 4) * 8 + jj;
      float wv = Wh[j * 64 + k];
      unsigned short hi = f2bf(wv);
      WhFhi[(jt * 2 + kh) * 512 + lane * 8 + jj] = hi;
      WhFlo[(jt * 2 + kh) * 512 + lane * 8 + jj] = f2bf(wv - bf2f(hi));
    }
  }
}

// ---------------- embedding gather (bf16 hi/lo master) ----------------
__global__ void k_embed(const int* __restrict__ nodes, const float* __restrict__ emb,
                        unsigned short* __restrict__ hi_a,
                        unsigned short* __restrict__ lo) {
  int gid = blockIdx.x * 256 + threadIdx.x;     // N*64 = 50000*256 exact
  int i = gid >> 6, c = gid & 63;
  float v = emb[nodes[i] * 64 + c];
  unsigned short h = f2bf(v);
  hi_a[gid] = h;
  lo[gid] = f2bf(v - bf2f(h));
}

// ---------------- fused layer (round-13 champion, verbatim) -----------------
// Cross-direction interleaved gather: per group iteration, dir0's 16 gathers
// AND dir1's 16 gathers are issued back-to-back (32 independent loads in
// flight), then dir0 accumulates (its waitcnt leaves dir1's loads
// outstanding), then dir1 accumulates. Two independent accumulator states
// make the overlap structural dataflow. LDS-reused y-transpose epilogue.
__global__ __launch_bounds__(256, 6) void k_layer(
    const unsigned short* __restrict__ hi_in,      // gather source + master hi
    unsigned short* __restrict__ hi_out,
    unsigned short* __restrict__ lo,               // master lo (in-place)
    const int* __restrict__ rp0, const int* __restrict__ ci0,
    const int* __restrict__ rp1, const int* __restrict__ ci1,
    const unsigned short* __restrict__ WfL, const float* __restrict__ bpL) {
  __shared__ __align__(16) unsigned short m_s[4][2][16 * 72];  // [warp][dir], bf16, pitch 72
  __shared__ float bp_s[128];
  int tid = threadIdx.x, lane = tid & 63, w = tid >> 6;
  if (tid < 128) bp_s[tid] = bpL[tid];
  __syncthreads();
  int base = (blockIdx.x * 4 + w) * 16;
  int n15 = lane & 15, q = lane >> 4;

  // rp for BOTH dirs into registers; first two ci blocks of BOTH dirs in flight
  int rpv0 = (lane < 17) ? rp0[base + lane] : 0;
  int rpv1 = (lane < 17) ? rp1[base + lane] : 0;
  int rs0 = __builtin_amdgcn_readlane(rpv0, 0);
  int re0 = __builtin_amdgcn_readlane(rpv0, 16);
  int rs1 = __builtin_amdgcn_readlane(rpv1, 0);
  int re1 = __builtin_amdgcn_readlane(rpv1, 16);
  int nb0 = re0 - rs0, nb1 = re1 - rs1;

  int cv0  = (lane < nb0)      ? ci0[rs0 + lane]      : 0;
  int cv1  = (lane < nb1)      ? ci1[rs1 + lane]      : 0;
  int cv0n = (64 + lane < nb0) ? ci0[rs0 + 64 + lane] : 0;
  int cv1n = (64 + lane < nb1) ? ci1[rs1 + 64 + lane] : 0;

  int cur0 = 0, cs0 = rs0, ce0 = __builtin_amdgcn_readlane(rpv0, 1);
  int cur1 = 0, cs1 = rs1, ce1 = __builtin_amdgcn_readlane(rpv1, 1);
  float a0 = 0.f, a1 = 0.f;

  int g0max = (nb0 + 15) >> 4, g1max = (nb1 + 15) >> 4;
  int gmax = g0max > g1max ? g0max : g1max;

  for (int g = 0; g < gmax; ++g) {
    int off = g << 4;
    int boff = off & 63;
    if (g && boff == 0) {                      // 64-block rollover (every 4 groups)
      cv0 = cv0n; cv1 = cv1n;
      cv0n = (off + 64 + lane < nb0) ? ci0[rs0 + off + 64 + lane] : 0;
      cv1n = (off + 64 + lane < nb1) ? ci1[rs1 + off + 64 + lane] : 0;
    }
    bool do0 = off < nb0, do1 = off < nb1;
    float v0[16], v1[16];
    if (do0) {                                 // issue dir0 gathers (16 in flight)
      #pragma unroll
      for (int u = 0; u < 16; ++u) {
        int sn = __builtin_amdgcn_readlane(cv0, boff + u);  // OOB lanes hold 0 -> safe row
        v0[u] = bf2f(hi_in[sn * 64 + lane]);
      }
    }
    if (do1) {                                 // issue dir1 gathers (now 32 in flight)
      #pragma unroll
      for (int u = 0; u < 16; ++u) {
        int sn = __builtin_amdgcn_readlane(cv1, boff + u);
        v1[u] = bf2f(hi_in[sn * 64 + lane]);
      }
    }
    if (do0) {                                 // accumulate dir0 (dir1 loads in flight)
      int jb = rs0 + off;
      #pragma unroll
      for (int u = 0; u < 16; ++u) {
        int j = jb + u;
        if (j < re0) {
          while (j >= ce0) {                   // flush node cur0
            int deg = ce0 - cs0;
            float invc = deg > 0 ? __builtin_amdgcn_rcpf((float)deg) : 0.f;
            m_s[w][0][cur0 * 72 + lane] = f2bf(a0 * invc);
            a0 = 0.f; cur0++; cs0 = ce0;
            ce0 = __builtin_amdgcn_readlane(rpv0, cur0 + 1);
          }
          a0 += v0[u];
        }
      }
    }
    if (do1) {                                 // accumulate dir1
      int jb = rs1 + off;
      #pragma unroll
      for (int u = 0; u < 16; ++u) {
        int j = jb + u;
        if (j < re1) {
          while (j >= ce1) {                   // flush node cur1
            int deg = ce1 - cs1;
            float invc = deg > 0 ? __builtin_amdgcn_rcpf((float)deg) : 0.f;
            m_s[w][1][cur1 * 72 + lane] = f2bf(a1 * invc);
            a1 = 0.f; cur1++; cs1 = ce1;
            ce1 = __builtin_amdgcn_readlane(rpv1, cur1 + 1);
          }
          a1 += v1[u];
        }
      }
    }
  }
  #pragma unroll 1
  while (cur0 < 16) {                          // trailing flush dir0
    int deg = ce0 - cs0;
    float invc = deg > 0 ? __builtin_amdgcn_rcpf((float)deg) : 0.f;
    m_s[w][0][cur0 * 72 + lane] = f2bf(a0 * invc);
    a0 = 0.f; cs0 = ce0; cur0++;
    if (cur0 < 16) ce0 = __builtin_amdgcn_readlane(rpv0, cur0 + 1);
  }
  #pragma unroll 1
  while (cur1 < 16) {                          // trailing flush dir1
    int deg = ce1 - cs1;
    float invc = deg > 0 ? __builtin_amdgcn_rcpf((float)deg) : 0.f;
    m_s[w][1][cur1 * 72 + lane] = f2bf(a1 * invc);
    a1 = 0.f; cs1 = ce1; cur1++;
    if (cur1 < 16) ce1 = __builtin_amdgcn_readlane(rpv1, cur1 + 1);
  }

  // -------- MFMA both dirs; y into warp-private LDS scratch (reuses m_s) ----
  bf16x8 b0d0 = *(const bf16x8*)&m_s[w][0][n15 * 72 + q * 8];
  bf16x8 b1d0 = *(const bf16x8*)&m_s[w][0][n15 * 72 + 32 + q * 8];
  bf16x8 b0d1 = *(const bf16x8*)&m_s[w][1][n15 * 72 + q * 8];
  bf16x8 b1d1 = *(const bf16x8*)&m_s[w][1][n15 * 72 + 32 + q * 8];
  float* ys = (float*)&m_s[w][0][0];                   // 4352 B <= 4608 B region
  #pragma unroll
  for (int ct = 0; ct < 4; ++ct) {
    const unsigned short* wf0 = WfL + (ct * 2) * 512 + lane * 8;        // d0 frags
    const unsigned short* wf1 = WfL + 4096 + (ct * 2) * 512 + lane * 8; // d1 frags
    floatx4 d40 = {0.f, 0.f, 0.f, 0.f};
    floatx4 d41 = {0.f, 0.f, 0.f, 0.f};
    d40 = __builtin_amdgcn_mfma_f32_16x16x32_bf16(*(const bf16x8*)wf0, b0d0, d40, 0, 0, 0);
    d40 = __builtin_amdgcn_mfma_f32_16x16x32_bf16(*(const bf16x8*)(wf0 + 512), b1d0, d40, 0, 0, 0);
    d41 = __builtin_amdgcn_mfma_f32_16x16x32_bf16(*(const bf16x8*)wf1, b0d1, d41, 0, 0, 0);
    d41 = __builtin_amdgcn_mfma_f32_16x16x32_bf16(*(const bf16x8*)(wf1 + 512), b1d1, d41, 0, 0, 0);
    // D: col = n15 = node, row = ct*16 + q*4 + i = channel
    int c0 = ct * 16 + q * 4;
    floatx4 yv;
    #pragma unroll
    for (int i = 0; i < 4; ++i)
      yv[i] = fmaxf(d40[i] + bp_s[c0 + i], 0.f)
            + fmaxf(d41[i] + bp_s[64 + c0 + i], 0.f);
    *(floatx4*)&ys[n15 * 68 + c0] = yv;                // pitch 68 f32
  }

  // epilogue: row-major coalesced; residual on hi/lo, re-split, store
  #pragma unroll
  for (int r = 0; r < 16; ++r) {
    int gi = (base + r) * 64 + lane;
    float xv = bf2f(hi_in[gi]) + bf2f(lo[gi]) + ys[r * 68 + lane];
    unsigned short h = f2bf(xv);
    hi_out[gi] = h;
    lo[gi] = f2bf(xv - bf2f(h));   // in-place: only this warp touches these rows
  }
}

// ---------------- readout (MFMA; hi/lo split comes free from master format) ----
__global__ __launch_bounds__(256) void k_final(
    const unsigned short* __restrict__ hi, const unsigned short* __restrict__ lo,
    const int* __restrict__ rules,
    const unsigned short* __restrict__ WhFhi, const unsigned short* __restrict__ WhFlo,
    const float* __restrict__ bh, const float* __restrict__ Wo,
    float* __restrict__ out) {
  __shared__ __align__(16) float bh_s[1024], wo_s[1024];
  int tid = threadIdx.x, lane = tid & 63, w = tid >> 6;
  ((floatx4*)bh_s)[tid] = ((const floatx4*)bh)[tid];
  ((floatx4*)wo_s)[tid] = ((const floatx4*)Wo)[tid];
  __syncthreads();
  int n15 = lane & 15, q = lane >> 4;
  int rbase = (blockIdx.x * 4 + w) * 16;
  int ru = rbase + n15;
  int nd = rules[ru < N_RULES ? ru : N_RULES - 1];
  bf16x8 b0h = *(const bf16x8*)&hi[nd * 64 + q * 8];
  bf16x8 b1h = *(const bf16x8*)&hi[nd * 64 + 32 + q * 8];
  bf16x8 b0l = *(const bf16x8*)&lo[nd * 64 + q * 8];
  bf16x8 b1l = *(const bf16x8*)&lo[nd * 64 + 32 + q * 8];
  float acc = 0.f;
  #pragma unroll 4
  for (int jt = 0; jt < 64; ++jt) {
    const unsigned short* fh = WhFhi + (jt * 2) * 512 + lane * 8;
    const unsigned short* fl = WhFlo + (jt * 2) * 512 + lane * 8;
    bf16x8 a0h = *(const bf16x8*)fh;
    bf16x8 a1h = *(const bf16x8*)(fh + 512);
    bf16x8 a0l = *(const bf16x8*)fl;
    bf16x8 a1l = *(const bf16x8*)(fl + 512);
    floatx4 d4 = {0.f, 0.f, 0.f, 0.f};
    d4 = __builtin_amdgcn_mfma_f32_16x16x32_bf16(a0h, b0h, d4, 0, 0, 0);
    d4 = __builtin_amdgcn_mfma_f32_16x16x32_bf16(a1h, b1h, d4, 0, 0, 0);
    d4 = __builtin_amdgcn_mfma_f32_16x16x32_bf16(a0h, b0l, d4, 0, 0, 0);
    d4 = __builtin_amdgcn_mfma_f32_16x16x32_bf16(a1h, b1l, d4, 0, 0, 0);
    d4 = __builtin_amdgcn_mfma_f32_16x16x32_bf16(a0l, b0h, d4, 0, 0, 0);
    d4 = __builtin_amdgcn_mfma_f32_16x16x32_bf16(a1l, b1h, d4, 0, 0, 0);
    floatx4 bh4 = *(const floatx4*)&bh_s[jt * 16 + q * 4];
    floatx4 wo4 = *(const floatx4*)&wo_s[jt * 16 + q * 4];
    #pragma unroll
    for (int i = 0; i < 4; ++i)
      acc += fmaxf(d4[i] + bh4[i], 0.f) * wo4[i];
  }
  acc += __shfl_down(acc, 32);     // fold q2,q3 into q0,q1
  acc += __shfl_down(acc, 16);     // fold q1 into q0
  if (lane < 16 && rbase + lane < N_RULES) out[rbase + lane] = acc;
}

// ---------------- launch ----------------
extern "C" void kernel_launch(void* const* d_in, const int* in_sizes, int n_in,
                              void* d_out, int out_size, void* d_ws, size_t ws_size,
                              hipStream_t stream) {
  const int* nodes = (const int*)d_in[0];
  const int* sources = (const int*)d_in[1];
  const int* targets = (const int*)d_in[2];
  const int* rules = (const int*)d_in[3];
  const float* emb = (const float*)d_in[4];
  const float* W = (const float*)d_in[5];
  const float* b = (const float*)d_in[6];
  const float* gamma = (const float*)d_in[7];
  const float* beta = (const float*)d_in[8];
  const float* rmean = (const float*)d_in[9];
  const float* rvar = (const float*)d_in[10];
  const float* Wh = (const float*)d_in[11];
  const float* bh = (const float*)d_in[12];
  const float* Wo = (const float*)d_in[13];
  float* out = (float*)d_out;

  if (ws_size < 95100000u) return;  // need ~95.1 MB scratch

  char* ws = (char*)d_ws;
  unsigned short* hi_a = (unsigned short*)(ws + 0);          // 25.6 MB
  unsigned short* hi_b = (unsigned short*)(ws + 25600000);   // 25.6 MB
  unsigned short* lo   = (unsigned short*)(ws + 51200000);   // 25.6 MB
  int* deg_out  = (int*)(ws + 76800000);                     // 800 KB
  int* deg_back = (int*)(ws + 77600000);                     // 800 KB
  int* rpc      = (int*)(ws + 78400000);                     // 1.6 MB (2 x N_NODES)
  int* rp_out   = (int*)(ws + 84800000);                     // RP_STRIDE ints
  int* rp_back  = (int*)(ws + 85600256);
  int* ci_out   = (int*)(ws + 86400512);                     // 3.2 MB
  int* ci_back  = (int*)(ws + 89600512);                     // 3.2 MB
  int* part     = (int*)(ws + 92800512);                     // 1568 B
  unsigned short* WpF   = (unsigned short*)(ws + 92802080);  // 384 KB (16B aligned)
  float* bp             = (float*)(ws + 93195296);           // 12 KB
  unsigned short* WhFhi = (unsigned short*)(ws + 93207584);  // 128 KB
  unsigned short* WhFlo = (unsigned short*)(ws + 93338656);  // 128 KB -> ends 93,469,728

  // zero deg_out/deg_back (contiguous 1.6 MB)
  (void)hipMemsetAsync(deg_out, 0, 1600000u, stream);

  k_hist<<<3125, 256, 0, stream>>>(sources, targets, deg_out, deg_back);
  k_scanA<<<dim3(SCAN_NB, 2), 256, 0, stream>>>(deg_out, part);
  k_scanB<<<dim3(1, 2), 256, 0, stream>>>(part, rp_out);
  k_scanC<<<dim3(SCAN_NB, 2), 256, 0, stream>>>(deg_out, part, rp_out, rpc);
  k_fill<<<3125, 256, 0, stream>>>(sources, targets, rpc, rpc + N_NODES,
                                   ci_out, ci_back);
  k_prep<<<dim3(2, NLAYERS), 64, 0, stream>>>(W, b, gamma, beta, rmean, rvar, WpF, bp);
  k_prep2<<<64, 64, 0, stream>>>(Wh, WhFhi, WhFlo);
  k_embed<<<50000, 256, 0, stream>>>(nodes, emb, hi_a, lo);

  const unsigned short* hin = hi_a;
  unsigned short* hout = hi_b;
  for (int l = 0; l < NLAYERS; ++l) {
    k_layer<<<3125, 256, 0, stream>>>(hin, hout, lo,
                                      rp_out, ci_out, rp_back, ci_back,
                                      WpF + (size_t)l * 8192, bp + (size_t)l * 128);
    const unsigned short* tmp = hin; hin = hout; hout = (unsigned short*)tmp;
  }
  k_final<<<782, 256, 0, stream>>>(hin, lo, rules, WhFhi, WhFlo, bh, Wo, out);
}

// Round 11
// 1489.499 us; speedup vs baseline: 1.6451x; 1.0791x over previous
//
#include <hip/hip_runtime.h>

#define N_NODES 200000
#define N_EDGES 800000
#define N_RULES 50000
#define NLAYERS 24
#define SCAN_NB 196        // ceil(200000/1024)
#define RP_STRIDE 200064   // ints per rp array (padded)

typedef short bf16x8 __attribute__((ext_vector_type(8)));
typedef float floatx4 __attribute__((ext_vector_type(4)));

__device__ __forceinline__ unsigned short f2bf(float f) {
  unsigned int b = __float_as_uint(f);
  b += 0x7FFFu + ((b >> 16) & 1u);          // round-to-nearest-even
  return (unsigned short)(b >> 16);
}
__device__ __forceinline__ float bf2f(unsigned short u) {
  return __uint_as_float(((unsigned int)u) << 16);
}

// ---------------- CSR build (unpadded; rank captured in hist) ----------------

__global__ void k_hist(const int* __restrict__ src, const int* __restrict__ tgt,
                       int* __restrict__ deg_out, int* __restrict__ deg_back,
                       int* __restrict__ rank_out, int* __restrict__ rank_back) {
  int e = blockIdx.x * 256 + threadIdx.x;   // E = 3125*256 exact
  rank_out[e]  = atomicAdd(&deg_out[tgt[e]], 1);   // rank = old count
  rank_back[e] = atomicAdd(&deg_back[src[e]], 1);
}

__global__ void k_scanA(const int* __restrict__ deg, int* __restrict__ part) {
  int y = blockIdx.y;
  const int* d = deg + y * N_NODES;
  __shared__ int sh[256];
  int t = threadIdx.x;
  int base = blockIdx.x * 1024 + t * 4;
  int s = 0;
  #pragma unroll
  for (int k = 0; k < 4; ++k) { int i = base + k; if (i < N_NODES) s += d[i]; }
  sh[t] = s; __syncthreads();
  for (int off = 128; off > 0; off >>= 1) { if (t < off) sh[t] += sh[t + off]; __syncthreads(); }
  if (t == 0) part[y * SCAN_NB + blockIdx.x] = sh[0];
}

__global__ void k_scanB(int* __restrict__ part, int* __restrict__ rp) {
  int y = blockIdx.y;
  __shared__ int buf[256];
  int t = threadIdx.x;
  int v = (t < SCAN_NB) ? part[y * SCAN_NB + t] : 0;
  buf[t] = v; __syncthreads();
  for (int off = 1; off < 256; off <<= 1) {
    int x = (t >= off) ? buf[t - off] : 0;
    __syncthreads();
    buf[t] += x;
    __syncthreads();
  }
  if (t < SCAN_NB) part[y * SCAN_NB + t] = buf[t] - v;   // exclusive
  if (t == 0) rp[y * RP_STRIDE + N_NODES] = N_EDGES;
}

__global__ void k_scanC(const int* __restrict__ deg, const int* __restrict__ part,
                        int* __restrict__ rp) {
  int y = blockIdx.y;
  const int* d = deg + y * N_NODES;
  int* r = rp + y * RP_STRIDE;
  __shared__ int buf[256];
  int t = threadIdx.x;
  int base = blockIdx.x * 1024 + t * 4;
  int dv[4]; int s = 0;
  #pragma unroll
  for (int k = 0; k < 4; ++k) { int i = base + k; dv[k] = (i < N_NODES) ? d[i] : 0; s += dv[k]; }
  buf[t] = s; __syncthreads();
  int sv = s;
  for (int off = 1; off < 256; off <<= 1) {
    int x = (t >= off) ? buf[t - off] : 0;
    __syncthreads();
    buf[t] += x;
    __syncthreads();
  }
  int e = part[y * SCAN_NB + blockIdx.x] + buf[t] - sv;
  #pragma unroll
  for (int k = 0; k < 4; ++k) { int i = base + k; if (i < N_NODES) r[i] = e; e += dv[k]; }
}

// atomic-free fill: slot = rp[node] + rank[e]
__global__ void k_fill(const int* __restrict__ src, const int* __restrict__ tgt,
                       const int* __restrict__ rp_out, const int* __restrict__ rp_back,
                       const int* __restrict__ rank_out, const int* __restrict__ rank_back,
                       int* __restrict__ ci_out, int* __restrict__ ci_back) {
  int e = blockIdx.x * 256 + threadIdx.x;
  int s = src[e], t = tgt[e];
  ci_out[rp_out[t] + rank_out[e]] = s;
  ci_back[rp_back[s] + rank_back[e]] = t;
}

// ---------------- BN-folded weight prep (bf16 MFMA A-fragments) ----------------
__global__ void k_prep(const float* __restrict__ W, const float* __restrict__ b,
                       const float* __restrict__ gamma, const float* __restrict__ beta,
                       const float* __restrict__ rmean, const float* __restrict__ rvar,
                       unsigned short* __restrict__ WpF, float* __restrict__ bp) {
  int d = blockIdx.x, l = blockIdx.y, lane = threadIdx.x;
  int ld = l * 2 + d;
  __shared__ float s_s[64], t_s[64];
  float s = gamma[ld * 64 + lane] * rsqrtf(rvar[ld * 64 + lane] + 1e-5f);
  s_s[lane] = s;
  t_s[lane] = beta[ld * 64 + lane] - rmean[ld * 64 + lane] * s;
  __syncthreads();
  float bias = b[ld * 64 + lane];
  for (int j = 0; j < 64; ++j) bias += W[(ld * 64 + lane) * 64 + j] * t_s[j];
  bp[ld * 64 + lane] = bias;
  #pragma unroll
  for (int f = 0; f < 8; ++f) {
    int ct = f >> 1, kh = f & 1;
    int row = ct * 16 + (lane & 15);
    #pragma unroll
    for (int jj = 0; jj < 8; ++jj) {
      int k = kh * 32 + (lane >> 4) * 8 + jj;
      float val = W[(ld * 64 + row) * 64 + k] * s_s[k];
      WpF[(ld * 8 + f) * 512 + lane * 8 + jj] = f2bf(val);
    }
  }
}

// ---------------- Wh prep: split bf16 hi/lo MFMA A-fragments ----------------
__global__ void k_prep2(const float* __restrict__ Wh,
                        unsigned short* __restrict__ WhFhi,
                        unsigned short* __restrict__ WhFlo) {
  int jt = blockIdx.x, lane = threadIdx.x;
  #pragma unroll
  for (int kh = 0; kh < 2; ++kh) {
    #pragma unroll
    for (int jj = 0; jj < 8; ++jj) {
      int j = jt * 16 + (lane & 15);
      int k = kh * 32 + (lane >> 4) * 8 + jj;
      float wv = Wh[j * 64 + k];
      unsigned short hi = f2bf(wv);
      WhFhi[(jt * 2 + kh) * 512 + lane * 8 + jj] = hi;
      WhFlo[(jt * 2 + kh) * 512 + lane * 8 + jj] = f2bf(wv - bf2f(hi));
    }
  }
}

// ---------------- embedding gather (bf16 hi/lo master) ----------------
__global__ void k_embed(const int* __restrict__ nodes, const float* __restrict__ emb,
                        unsigned short* __restrict__ hi_a,
                        unsigned short* __restrict__ lo) {
  int gid = blockIdx.x * 256 + threadIdx.x;     // N*64 = 50000*256 exact
  int i = gid >> 6, c = gid & 63;
  float v = emb[nodes[i] * 64 + c];
  unsigned short h = f2bf(v);
  hi_a[gid] = h;
  lo[gid] = f2bf(v - bf2f(h));
}

// ---------------- fused layer (round-13 champion, verbatim) -----------------
// Cross-direction interleaved gather: per group iteration, dir0's 16 gathers
// AND dir1's 16 gathers are issued back-to-back (32 independent loads in
// flight), then dir0 accumulates (its waitcnt leaves dir1's loads
// outstanding), then dir1 accumulates. Two independent accumulator states
// make the overlap structural dataflow. LDS-reused y-transpose epilogue.
__global__ __launch_bounds__(256, 6) void k_layer(
    const unsigned short* __restrict__ hi_in,      // gather source + master hi
    unsigned short* __restrict__ hi_out,
    unsigned short* __restrict__ lo,               // master lo (in-place)
    const int* __restrict__ rp0, const int* __restrict__ ci0,
    const int* __restrict__ rp1, const int* __restrict__ ci1,
    const unsigned short* __restrict__ WfL, const float* __restrict__ bpL) {
  __shared__ __align__(16) unsigned short m_s[4][2][16 * 72];  // [warp][dir], bf16, pitch 72
  __shared__ float bp_s[128];
  int tid = threadIdx.x, lane = tid & 63, w = tid >> 6;
  if (tid < 128) bp_s[tid] = bpL[tid];
  __syncthreads();
  int base = (blockIdx.x * 4 + w) * 16;
  int n15 = lane & 15, q = lane >> 4;

  // rp for BOTH dirs into registers; first two ci blocks of BOTH dirs in flight
  int rpv0 = (lane < 17) ? rp0[base + lane] : 0;
  int rpv1 = (lane < 17) ? rp1[base + lane] : 0;
  int rs0 = __builtin_amdgcn_readlane(rpv0, 0);
  int re0 = __builtin_amdgcn_readlane(rpv0, 16);
  int rs1 = __builtin_amdgcn_readlane(rpv1, 0);
  int re1 = __builtin_amdgcn_readlane(rpv1, 16);
  int nb0 = re0 - rs0, nb1 = re1 - rs1;

  int cv0  = (lane < nb0)      ? ci0[rs0 + lane]      : 0;
  int cv1  = (lane < nb1)      ? ci1[rs1 + lane]      : 0;
  int cv0n = (64 + lane < nb0) ? ci0[rs0 + 64 + lane] : 0;
  int cv1n = (64 + lane < nb1) ? ci1[rs1 + 64 + lane] : 0;

  int cur0 = 0, cs0 = rs0, ce0 = __builtin_amdgcn_readlane(rpv0, 1);
  int cur1 = 0, cs1 = rs1, ce1 = __builtin_amdgcn_readlane(rpv1, 1);
  float a0 = 0.f, a1 = 0.f;

  int g0max = (nb0 + 15) >> 4, g1max = (nb1 + 15) >> 4;
  int gmax = g0max > g1max ? g0max : g1max;

  for (int g = 0; g < gmax; ++g) {
    int off = g << 4;
    int boff = off & 63;
    if (g && boff == 0) {                      // 64-block rollover (every 4 groups)
      cv0 = cv0n; cv1 = cv1n;
      cv0n = (off + 64 + lane < nb0) ? ci0[rs0 + off + 64 + lane] : 0;
      cv1n = (off + 64 + lane < nb1) ? ci1[rs1 + off + 64 + lane] : 0;
    }
    bool do0 = off < nb0, do1 = off < nb1;
    float v0[16], v1[16];
    if (do0) {                                 // issue dir0 gathers (16 in flight)
      #pragma unroll
      for (int u = 0; u < 16; ++u) {
        int sn = __builtin_amdgcn_readlane(cv0, boff + u);  // OOB lanes hold 0 -> safe row
        v0[u] = bf2f(hi_in[sn * 64 + lane]);
      }
    }
    if (do1) {                                 // issue dir1 gathers (now 32 in flight)
      #pragma unroll
      for (int u = 0; u < 16; ++u) {
        int sn = __builtin_amdgcn_readlane(cv1, boff + u);
        v1[u] = bf2f(hi_in[sn * 64 + lane]);
      }
    }
    if (do0) {                                 // accumulate dir0 (dir1 loads in flight)
      int jb = rs0 + off;
      #pragma unroll
      for (int u = 0; u < 16; ++u) {
        int j = jb + u;
        if (j < re0) {
          while (j >= ce0) {                   // flush node cur0
            int deg = ce0 - cs0;
            float invc = deg > 0 ? __builtin_amdgcn_rcpf((float)deg) : 0.f;
            m_s[w][0][cur0 * 72 + lane] = f2bf(a0 * invc);
            a0 = 0.f; cur0++; cs0 = ce0;
            ce0 = __builtin_amdgcn_readlane(rpv0, cur0 + 1);
          }
          a0 += v0[u];
        }
      }
    }
    if (do1) {                                 // accumulate dir1
      int jb = rs1 + off;
      #pragma unroll
      for (int u = 0; u < 16; ++u) {
        int j = jb + u;
        if (j < re1) {
          while (j >= ce1) {                   // flush node cur1
            int deg = ce1 - cs1;
            float invc = deg > 0 ? __builtin_amdgcn_rcpf((float)deg) : 0.f;
            m_s[w][1][cur1 * 72 + lane] = f2bf(a1 * invc);
            a1 = 0.f; cur1++; cs1 = ce1;
            ce1 = __builtin_amdgcn_readlane(rpv1, cur1 + 1);
          }
          a1 += v1[u];
        }
      }
    }
  }
  #pragma unroll 1
  while (cur0 < 16) {                          // trailing flush dir0
    int deg = ce0 - cs0;
    float invc = deg > 0 ? __builtin_amdgcn_rcpf((float)deg) : 0.f;
    m_s[w][0][cur0 * 72 + lane] = f2bf(a0 * invc);
    a0 = 0.f; cs0 = ce0; cur0++;
    if (cur0 < 16) ce0 = __builtin_amdgcn_readlane(rpv0, cur0 + 1);
  }
  #pragma unroll 1
  while (cur1 < 16) {                          // trailing flush dir1
    int deg = ce1 - cs1;
    float invc = deg > 0 ? __builtin_amdgcn_rcpf((float)deg) : 0.f;
    m_s[w][1][cur1 * 72 + lane] = f2bf(a1 * invc);
    a1 = 0.f; cs1 = ce1; cur1++;
    if (cur1 < 16) ce1 = __builtin_amdgcn_readlane(rpv1, cur1 + 1);
  }

  // -------- MFMA both dirs; y into warp-private LDS scratch (reuses m_s) ----
  bf16x8 b0d0 = *(const bf16x8*)&m_s[w][0][n15 * 72 + q * 8];
  bf16x8 b1d0 = *(const bf16x8*)&m_s[w][0][n15 * 72 + 32 + q * 8];
  bf16x8 b0d1 = *(const bf16x8*)&m_s[w][1][n15 * 72 + q * 8];
  bf16x8 b1d1 = *(const bf16x8*)&m_s[w][1][n15 * 72 + 32 + q * 8];
  float* ys = (float*)&m_s[w][0][0];                   // 4352 B <= 4608 B region
  #pragma unroll
  for (int ct = 0; ct < 4; ++ct) {
    const unsigned short* wf0 = WfL + (ct * 2) * 512 + lane * 8;        // d0 frags
    const unsigned short* wf1 = WfL + 4096 + (ct * 2) * 512 + lane * 8; // d1 frags
    floatx4 d40 = {0.f, 0.f, 0.f, 0.f};
    floatx4 d41 = {0.f, 0.f, 0.f, 0.f};
    d40 = __builtin_amdgcn_mfma_f32_16x16x32_bf16(*(const bf16x8*)wf0, b0d0, d40, 0, 0, 0);
    d40 = __builtin_amdgcn_mfma_f32_16x16x32_bf16(*(const bf16x8*)(wf0 + 512), b1d0, d40, 0, 0, 0);
    d41 = __builtin_amdgcn_mfma_f32_16x16x32_bf16(*(const bf16x8*)wf1, b0d1, d41, 0, 0, 0);
    d41 = __builtin_amdgcn_mfma_f32_16x16x32_bf16(*(const bf16x8*)(wf1 + 512), b1d1, d41, 0, 0, 0);
    // D: col = n15 = node, row = ct*16 + q*4 + i = channel
    int c0 = ct * 16 + q * 4;
    floatx4 yv;
    #pragma unroll
    for (int i = 0; i < 4; ++i)
      yv[i] = fmaxf(d40[i] + bp_s[c0 + i], 0.f)
            + fmaxf(d41[i] + bp_s[64 + c0 + i], 0.f);
    *(floatx4*)&ys[n15 * 68 + c0] = yv;                // pitch 68 f32
  }

  // epilogue: row-major coalesced; residual on hi/lo, re-split, store
  #pragma unroll
  for (int r = 0; r < 16; ++r) {
    int gi = (base + r) * 64 + lane;
    float xv = bf2f(hi_in[gi]) + bf2f(lo[gi]) + ys[r * 68 + lane];
    unsigned short h = f2bf(xv);
    hi_out[gi] = h;
    lo[gi] = f2bf(xv - bf2f(h));   // in-place: only this warp touches these rows
  }
}

// ---------------- readout (MFMA; hi/lo split comes free from master format) ----
__global__ __launch_bounds__(256) void k_final(
    const unsigned short* __restrict__ hi, const unsigned short* __restrict__ lo,
    const int* __restrict__ rules,
    const unsigned short* __restrict__ WhFhi, const unsigned short* __restrict__ WhFlo,
    const float* __restrict__ bh, const float* __restrict__ Wo,
    float* __restrict__ out) {
  __shared__ __align__(16) float bh_s[1024], wo_s[1024];
  int tid = threadIdx.x, lane = tid & 63, w = tid >> 6;
  ((floatx4*)bh_s)[tid] = ((const floatx4*)bh)[tid];
  ((floatx4*)wo_s)[tid] = ((const floatx4*)Wo)[tid];
  __syncthreads();
  int n15 = lane & 15, q = lane >> 4;
  int rbase = (blockIdx.x * 4 + w) * 16;
  int ru = rbase + n15;
  int nd = rules[ru < N_RULES ? ru : N_RULES - 1];
  bf16x8 b0h = *(const bf16x8*)&hi[nd * 64 + q * 8];
  bf16x8 b1h = *(const bf16x8*)&hi[nd * 64 + 32 + q * 8];
  bf16x8 b0l = *(const bf16x8*)&lo[nd * 64 + q * 8];
  bf16x8 b1l = *(const bf16x8*)&lo[nd * 64 + 32 + q * 8];
  float acc = 0.f;
  #pragma unroll 4
  for (int jt = 0; jt < 64; ++jt) {
    const unsigned short* fh = WhFhi + (jt * 2) * 512 + lane * 8;
    const unsigned short* fl = WhFlo + (jt * 2) * 512 + lane * 8;
    bf16x8 a0h = *(const bf16x8*)fh;
    bf16x8 a1h = *(const bf16x8*)(fh + 512);
    bf16x8 a0l = *(const bf16x8*)fl;
    bf16x8 a1l = *(const bf16x8*)(fl + 512);
    floatx4 d4 = {0.f, 0.f, 0.f, 0.f};
    d4 = __builtin_amdgcn_mfma_f32_16x16x32_bf16(a0h, b0h, d4, 0, 0, 0);
    d4 = __builtin_amdgcn_mfma_f32_16x16x32_bf16(a1h, b1h, d4, 0, 0, 0);
    d4 = __builtin_amdgcn_mfma_f32_16x16x32_bf16(a0h, b0l, d4, 0, 0, 0);
    d4 = __builtin_amdgcn_mfma_f32_16x16x32_bf16(a1h, b1l, d4, 0, 0, 0);
    d4 = __builtin_amdgcn_mfma_f32_16x16x32_bf16(a0l, b0h, d4, 0, 0, 0);
    d4 = __builtin_amdgcn_mfma_f32_16x16x32_bf16(a1l, b1h, d4, 0, 0, 0);
    floatx4 bh4 = *(const floatx4*)&bh_s[jt * 16 + q * 4];
    floatx4 wo4 = *(const floatx4*)&wo_s[jt * 16 + q * 4];
    #pragma unroll
    for (int i = 0; i < 4; ++i)
      acc += fmaxf(d4[i] + bh4[i], 0.f) * wo4[i];
  }
  acc += __shfl_down(acc, 32);     // fold q2,q3 into q0,q1
  acc += __shfl_down(acc, 16);     // fold q1 into q0
  if (lane < 16 && rbase + lane < N_RULES) out[rbase + lane] = acc;
}

// ---------------- launch ----------------
extern "C" void kernel_launch(void* const* d_in, const int* in_sizes, int n_in,
                              void* d_out, int out_size, void* d_ws, size_t ws_size,
                              hipStream_t stream) {
  const int* nodes = (const int*)d_in[0];
  const int* sources = (const int*)d_in[1];
  const int* targets = (const int*)d_in[2];
  const int* rules = (const int*)d_in[3];
  const float* emb = (const float*)d_in[4];
  const float* W = (const float*)d_in[5];
  const float* b = (const float*)d_in[6];
  const float* gamma = (const float*)d_in[7];
  const float* beta = (const float*)d_in[8];
  const float* rmean = (const float*)d_in[9];
  const float* rvar = (const float*)d_in[10];
  const float* Wh = (const float*)d_in[11];
  const float* bh = (const float*)d_in[12];
  const float* Wo = (const float*)d_in[13];
  float* out = (float*)d_out;

  if (ws_size < 95100000u) return;  // need ~95.1 MB scratch

  char* ws = (char*)d_ws;
  unsigned short* hi_a = (unsigned short*)(ws + 0);          // 25.6 MB
  unsigned short* hi_b = (unsigned short*)(ws + 25600000);   // 25.6 MB
  unsigned short* lo   = (unsigned short*)(ws + 51200000);   // 25.6 MB
  int* deg_out  = (int*)(ws + 76800000);                     // 800 KB
  int* deg_back = (int*)(ws + 77600000);                     // 800 KB
  int* rank_out = (int*)(ws + 78400000);                     // 3.2 MB
  int* rank_back= (int*)(ws + 81600000);                     // 3.2 MB
  int* rp_out   = (int*)(ws + 84800000);                     // RP_STRIDE ints
  int* rp_back  = (int*)(ws + 85600256);
  int* ci_out   = (int*)(ws + 86400512);                     // 3.2 MB
  int* ci_back  = (int*)(ws + 89600512);                     // 3.2 MB
  int* part     = (int*)(ws + 92800512);                     // 1568 B
  unsigned short* WpF   = (unsigned short*)(ws + 92802080);  // 384 KB (16B aligned)
  float* bp             = (float*)(ws + 93195296);           // 12 KB
  unsigned short* WhFhi = (unsigned short*)(ws + 93207584);  // 128 KB
  unsigned short* WhFlo = (unsigned short*)(ws + 93338656);  // 128 KB -> ends 93,469,728

  // zero deg_out/deg_back (contiguous 1.6 MB)
  (void)hipMemsetAsync(deg_out, 0, 1600000u, stream);

  k_hist<<<3125, 256, 0, stream>>>(sources, targets, deg_out, deg_back,
                                   rank_out, rank_back);
  k_scanA<<<dim3(SCAN_NB, 2), 256, 0, stream>>>(deg_out, part);
  k_scanB<<<dim3(1, 2), 256, 0, stream>>>(part, rp_out);
  k_scanC<<<dim3(SCAN_NB, 2), 256, 0, stream>>>(deg_out, part, rp_out);
  k_fill<<<3125, 256, 0, stream>>>(sources, targets, rp_out, rp_back,
                                   rank_out, rank_back, ci_out, ci_back);
  k_prep<<<dim3(2, NLAYERS), 64, 0, stream>>>(W, b, gamma, beta, rmean, rvar, WpF, bp);
  k_prep2<<<64, 64, 0, stream>>>(Wh, WhFhi, WhFlo);
  k_embed<<<50000, 256, 0, stream>>>(nodes, emb, hi_a, lo);

  const unsigned short* hin = hi_a;
  unsigned short* hout = hi_b;
  for (int l = 0; l < NLAYERS; ++l) {
    k_layer<<<3125, 256, 0, stream>>>(hin, hout, lo,
                                      rp_out, ci_out, rp_back, ci_back,
                                      WpF + (size_t)l * 8192, bp + (size_t)l * 128);
    const unsigned short* tmp = hin; hin = hout; hout = (unsigned short*)tmp;
  }
  k_final<<<782, 256, 0, stream>>>(hin, lo, rules, WhFhi, WhFlo, bh, Wo, out);
}